// Round 2
// baseline (11988.463 us; speedup 1.0000x reference)
//
#include <hip/hip_runtime.h>
#include <hip/hip_bf16.h>

#define B_  256
#define T_  1024
#define D_  256
#define H_  512
#define G_  2048   // 4*H
#define KT_ 768    // H + D

// ws layout (bytes)
#define WPACK_OFF 0                        // 2048*768*2 = 3145728
#define BIAS_OFF  3145728                  // 2048*4     = 8192
#define H0_OFF    (BIAS_OFF + 8192)        // 256*512*2  = 262144
#define H1_OFF    (H0_OFF + 262144)
#define C_OFF     (H1_OFF + 262144)        // 256*512*4  = 524288 (fallback path only)
#define CTR_OFF   (C_OFF + 524288)         // 512 uints  = 2048

typedef __attribute__((ext_vector_type(8))) short bf16x8;
typedef __attribute__((ext_vector_type(4))) float f32x4;

__device__ __forceinline__ unsigned short f2bf(float f) {
    unsigned int u = __float_as_uint(f);
    u = (u + 0x7fffu + ((u >> 16) & 1u)) >> 16;   // RNE
    return (unsigned short)u;
}
__device__ __forceinline__ float bf2f(unsigned short s) {
    return __uint_as_float(((unsigned int)s) << 16);
}
__device__ __forceinline__ float sigm(float v) { return 1.0f / (1.0f + __expf(-v)); }
__device__ __forceinline__ float tanh_(float v) { return 2.0f / (1.0f + __expf(-2.0f * v)) - 1.0f; }

// ---- prep: pack [W_hh | W_ih] rows into bf16 Wpack[2048][768] ----
__global__ __launch_bounds__(256) void build_wpack(const float* __restrict__ Whh,
                                                   const float* __restrict__ Wih,
                                                   unsigned short* __restrict__ wpack) {
    int idx = blockIdx.x * 256 + threadIdx.x;      // 0..196607, each = 8 elems
    int g = idx / 96, cc = idx % 96, k = cc * 8;
    const float* src = (k < H_) ? (Whh + (size_t)g * H_ + k)
                                : (Wih + (size_t)g * D_ + (k - H_));
    union { unsigned short us[8]; uint4 v; } u;
#pragma unroll
    for (int i = 0; i < 8; ++i) u.us[i] = f2bf(src[i]);
    *(uint4*)(wpack + (size_t)idx * 8) = u.v;
}

// ---- prep: zero h0/h1/c, build bias, zero barrier counters ----
__global__ __launch_bounds__(256) void init_misc(const float* __restrict__ bih,
                                                 const float* __restrict__ bhh,
                                                 float* __restrict__ bias,
                                                 unsigned int* __restrict__ zreg,
                                                 unsigned int* __restrict__ ctr) {
    int gid = blockIdx.x * 256 + threadIdx.x;      // grid 1024 -> 262144
    zreg[gid] = 0u;                                // h0+h1+c region (1 MB)
    if (gid < G_) bias[gid] = bih[gid] + bhh[gid];
    if (gid < 512) ctr[gid] = 0u;
}

// ============ persistent cooperative LSTM ============
// grid 256 = 8 rowgroups (32 rows) x 32 colgroups (16 j).  512 threads = 8 waves.
// wave w: rt=(w>>2)&1 (16-row tile), np=(w>>1)&1 (gate pair), kh=w&1 (K half).
// W fragments live in VGPRs for the whole T loop.  c lives in 1 reg/thread.
__global__ __launch_bounds__(512, 2) void lstm_persist(
    const float* __restrict__ x,
    const unsigned short* __restrict__ wpack,
    const float* __restrict__ bias,
    unsigned short* __restrict__ h0,
    unsigned short* __restrict__ h1,
    unsigned int* __restrict__ ctr)
{
    __shared__ __align__(16) unsigned char As[32 * 1536];   // [32 rows][768 k] bf16, swizzled
    __shared__ float Cs[2][32][66];                          // k-half partial gate sums

    const int tid  = threadIdx.x;
    const int lane = tid & 63, w = tid >> 6;
    const int rt = (w >> 2) & 1, np = (w >> 1) & 1, kh = w & 1;
    const int rg = blockIdx.x >> 5, cg = blockIdx.x & 31;
    const int r0 = rg * 32;

    // ---- load this wave's W fragments into registers (once) ----
    bf16x8 bfr[2][12];
#pragma unroll
    for (int nt2 = 0; nt2 < 2; ++nt2) {
        int gate = np * 2 + nt2;
        const unsigned short* wrow = wpack + (size_t)(gate * H_ + cg * 16 + (lane & 15)) * KT_;
#pragma unroll
        for (int ks = 0; ks < 12; ++ks) {
            int k = kh * 384 + ks * 32 + ((lane >> 4) * 8);
            bfr[nt2][ks] = *(const bf16x8*)(wrow + k);
        }
    }

    // ---- epilogue constants ----
    const int erow = tid >> 4;        // 0..31
    const int ejj  = tid & 15;
    const float bI = bias[0 * H_ + cg * 16 + ejj];
    const float bF = bias[1 * H_ + cg * 16 + ejj];
    const float bG = bias[2 * H_ + cg * 16 + ejj];
    const float bO = bias[3 * H_ + cg * 16 + ejj];
    float c_reg = 0.f;

    unsigned int* myctr = ctr + rg * 64;   // 256B-separated counters per rowgroup
    const int arow = rt * 16 + (lane & 15);
    const int koff = (lane >> 4) * 16;     // byte offset within 64B k-step

    for (int t = 0; t < T_; ++t) {
        const unsigned short* hin = (t & 1) ? h1 : h0;
        unsigned short*      hout = (t & 1) ? h0 : h1;

        // ---- stage A: h part (k 0..511) ----
#pragma unroll
        for (int p = 0; p < 4; ++p) {
            int idx = p * 512 + tid;
            int row = idx >> 6, seg = idx & 63;
            uint4 v = *(const uint4*)(hin + (size_t)(r0 + row) * H_ + seg * 8);
            *(uint4*)(As + ((row * 1536 + seg * 16) ^ ((row & 7) << 4))) = v;
        }
        // ---- stage A: x part (k 512..767), f32 -> bf16 ----
        {
            int row = tid >> 4, d0 = (tid & 15) * 16;
            const float* sp = x + ((size_t)(r0 + row) * T_ + t) * D_ + d0;
            float4 a = *(const float4*)sp;
            float4 b = *(const float4*)(sp + 4);
            float4 c2 = *(const float4*)(sp + 8);
            float4 d2 = *(const float4*)(sp + 12);
            union { unsigned short us[8]; uint4 v; } u0, u1;
            u0.us[0] = f2bf(a.x);  u0.us[1] = f2bf(a.y);  u0.us[2] = f2bf(a.z);  u0.us[3] = f2bf(a.w);
            u0.us[4] = f2bf(b.x);  u0.us[5] = f2bf(b.y);  u0.us[6] = f2bf(b.z);  u0.us[7] = f2bf(b.w);
            u1.us[0] = f2bf(c2.x); u1.us[1] = f2bf(c2.y); u1.us[2] = f2bf(c2.z); u1.us[3] = f2bf(c2.w);
            u1.us[4] = f2bf(d2.x); u1.us[5] = f2bf(d2.y); u1.us[6] = f2bf(d2.z); u1.us[7] = f2bf(d2.w);
            int kb = 1024 + d0 * 2;
            *(uint4*)(As + ((row * 1536 + kb) ^ ((row & 7) << 4)))      = u0.v;
            *(uint4*)(As + ((row * 1536 + kb + 16) ^ ((row & 7) << 4))) = u1.v;
        }
        __syncthreads();

        // ---- MFMA: 12 k-steps x 2 gate tiles ----
        f32x4 acc0 = {0.f, 0.f, 0.f, 0.f}, acc1 = {0.f, 0.f, 0.f, 0.f};
#pragma unroll
        for (int ks = 0; ks < 12; ++ks) {
            int kb = kh * 768 + ks * 64 + koff;
            bf16x8 av = *(const bf16x8*)(As + ((arow * 1536 + kb) ^ ((arow & 7) << 4)));
            acc0 = __builtin_amdgcn_mfma_f32_16x16x32_bf16(av, bfr[0][ks], acc0, 0, 0, 0);
            acc1 = __builtin_amdgcn_mfma_f32_16x16x32_bf16(av, bfr[1][ks], acc1, 0, 0, 0);
        }
        // dump partials (C layout: col=lane&15, row=(lane>>4)*4+reg)
#pragma unroll
        for (int reg = 0; reg < 4; ++reg) {
            int crow = rt * 16 + ((lane >> 4) * 4) + reg;
            Cs[kh][crow][(np * 2 + 0) * 16 + (lane & 15)] = acc0[reg];
            Cs[kh][crow][(np * 2 + 1) * 16 + (lane & 15)] = acc1[reg];
        }
        __syncthreads();

        // ---- cell update: thread owns (erow, ejj); c stays in register ----
        {
            float gi = Cs[0][erow][0 * 16 + ejj] + Cs[1][erow][0 * 16 + ejj] + bI;
            float gf = Cs[0][erow][1 * 16 + ejj] + Cs[1][erow][1 * 16 + ejj] + bF;
            float gg = Cs[0][erow][2 * 16 + ejj] + Cs[1][erow][2 * 16 + ejj] + bG;
            float go = Cs[0][erow][3 * 16 + ejj] + Cs[1][erow][3 * 16 + ejj] + bO;
            float I = sigm(gi), F = sigm(gf), Gv = tanh_(gg), O = sigm(go);
            c_reg = F * c_reg + I * Gv;
            hout[(size_t)(r0 + erow) * H_ + cg * 16 + ejj] = f2bf(O * tanh_(c_reg));
        }
        __syncthreads();   // all h stores drained (vmcnt(0)) before arrival

        // ---- rowgroup barrier: 32 blocks, monotone counter ----
        if (tid == 0) {
            __hip_atomic_fetch_add(myctr, 1u, __ATOMIC_RELEASE, __HIP_MEMORY_SCOPE_AGENT);
            unsigned int target = 32u * (unsigned)(t + 1);
            while (__hip_atomic_load(myctr, __ATOMIC_RELAXED, __HIP_MEMORY_SCOPE_AGENT) < target)
                __builtin_amdgcn_s_sleep(2);
            (void)__hip_atomic_load(myctr, __ATOMIC_ACQUIRE, __HIP_MEMORY_SCOPE_AGENT);
        }
        __syncthreads();
    }
}

// ============ fallback per-step kernel (round-1, known passing) ============
__global__ __launch_bounds__(256) void lstm_step(const float* __restrict__ x,
                                                 const unsigned short* __restrict__ wpack,
                                                 const float* __restrict__ bias,
                                                 const unsigned short* __restrict__ hin,
                                                 unsigned short* __restrict__ hout,
                                                 float* __restrict__ cbuf,
                                                 int t) {
    __shared__ __align__(16) unsigned char As[64 * 1536];
    __shared__ __align__(16) unsigned char Ws[128 * 256];

    const int tid = threadIdx.x;
    const int w = tid >> 6, lane = tid & 63;
    const int r0 = blockIdx.x * 64;
    const int j0 = blockIdx.y * 32;

#pragma unroll
    for (int p = 0; p < 16; ++p) {
        int idx = p * 256 + tid;
        int row = idx >> 6, seg = idx & 63;
        uint4 v = *(const uint4*)(hin + (size_t)(r0 + row) * H_ + seg * 8);
        *(uint4*)(As + (((row * 1536) + seg * 16) ^ ((row & 7) << 4))) = v;
    }
#pragma unroll
    for (int p = 0; p < 8; ++p) {
        int idx = p * 256 + tid;
        int row = idx >> 5, seg = idx & 31;
        const float* sp = x + ((size_t)(r0 + row) * T_ + t) * D_ + seg * 8;
        float4 a = *(const float4*)sp;
        float4 b = *(const float4*)(sp + 4);
        union { unsigned short us[8]; uint4 v; } u;
        u.us[0] = f2bf(a.x); u.us[1] = f2bf(a.y); u.us[2] = f2bf(a.z); u.us[3] = f2bf(a.w);
        u.us[4] = f2bf(b.x); u.us[5] = f2bf(b.y); u.us[6] = f2bf(b.z); u.us[7] = f2bf(b.w);
        *(uint4*)(As + (((row * 1536) + 1024 + seg * 16) ^ ((row & 7) << 4))) = u.v;
    }
    __syncthreads();

    f32x4 acc[8];
#pragma unroll
    for (int i = 0; i < 8; ++i) acc[i] = (f32x4){0.f, 0.f, 0.f, 0.f};

    for (int kc = 0; kc < 6; ++kc) {
#pragma unroll
        for (int p = 0; p < 8; ++p) {
            int idx = p * 256 + tid;
            int n = idx >> 4, seg = idx & 15;
            int g = n >> 5, jj = n & 31;
            uint4 v = *(const uint4*)(wpack + (size_t)(g * H_ + j0 + jj) * KT_ + kc * 128 + seg * 8);
            *(uint4*)(Ws + (((n * 256) + seg * 16) ^ ((n & 7) << 4))) = v;
        }
        __syncthreads();
#pragma unroll
        for (int ks = 0; ks < 4; ++ks) {
            int row = w * 16 + (lane & 15);
            int kb = (kc * 128 + ks * 32 + ((lane >> 4) * 8)) * 2;
            bf16x8 av = *(const bf16x8*)(As + ((row * 1536 + kb) ^ ((row & 7) << 4)));
            int kwb = (ks * 32 + ((lane >> 4) * 8)) * 2;
#pragma unroll
            for (int nt = 0; nt < 8; ++nt) {
                int n = (nt >> 1) * 32 + (nt & 1) * 16 + (lane & 15);
                bf16x8 bv = *(const bf16x8*)(Ws + ((n * 256 + kwb) ^ ((n & 7) << 4)));
                acc[nt] = __builtin_amdgcn_mfma_f32_16x16x32_bf16(av, bv, acc[nt], 0, 0, 0);
            }
        }
        __syncthreads();
    }

#pragma unroll
    for (int jt = 0; jt < 2; ++jt) {
        int jc = j0 + jt * 16 + (lane & 15);
        float bi = bias[jc], bf = bias[H_ + jc], bg = bias[2 * H_ + jc], bo = bias[3 * H_ + jc];
        f32x4 ai = acc[0 * 2 + jt];
        f32x4 af = acc[1 * 2 + jt];
        f32x4 ag = acc[2 * 2 + jt];
        f32x4 ao = acc[3 * 2 + jt];
#pragma unroll
        for (int reg = 0; reg < 4; ++reg) {
            int rb = r0 + w * 16 + ((lane >> 4) * 4) + reg;
            float I = sigm(ai[reg] + bi);
            float F = sigm(af[reg] + bf);
            float Gv = tanh_(ag[reg] + bg);
            float O = sigm(ao[reg] + bo);
            size_t ci = (size_t)rb * H_ + jc;
            float cn = F * cbuf[ci] + I * Gv;
            cbuf[ci] = cn;
            hout[ci] = f2bf(O * tanh_(cn));
        }
    }
}

// ---- final: out = sigmoid(h @ W_out^T + b_out), [256,2] ----
__global__ __launch_bounds__(256) void classify(const unsigned short* __restrict__ hbuf,
                                                const float* __restrict__ Wout,
                                                const float* __restrict__ bout,
                                                float* __restrict__ out) {
    int r = threadIdx.x;
    float a0 = 0.f, a1 = 0.f;
    for (int kk = 0; kk < H_ / 8; ++kk) {
        union { unsigned short us[8]; uint4 v; } u;
        u.v = *(const uint4*)(hbuf + (size_t)r * H_ + kk * 8);
#pragma unroll
        for (int i = 0; i < 8; ++i) {
            float hf = bf2f(u.us[i]);
            int k = kk * 8 + i;
            a0 += hf * Wout[k];
            a1 += hf * Wout[H_ + k];
        }
    }
    out[r * 2 + 0] = sigm(a0 + bout[0]);
    out[r * 2 + 1] = sigm(a1 + bout[1]);
}

extern "C" void kernel_launch(void* const* d_in, const int* in_sizes, int n_in,
                              void* d_out, int out_size, void* d_ws, size_t ws_size,
                              hipStream_t stream) {
    const float* x    = (const float*)d_in[0];
    const float* Wih  = (const float*)d_in[1];
    const float* Whh  = (const float*)d_in[2];
    const float* bih  = (const float*)d_in[3];
    const float* bhh  = (const float*)d_in[4];
    const float* Wout = (const float*)d_in[5];
    const float* bout = (const float*)d_in[6];
    float* out = (float*)d_out;
    char* ws = (char*)d_ws;

    unsigned short* wpack = (unsigned short*)(ws + WPACK_OFF);
    float*          bias  = (float*)(ws + BIAS_OFF);
    unsigned short* h0    = (unsigned short*)(ws + H0_OFF);
    unsigned short* h1    = (unsigned short*)(ws + H1_OFF);
    float*          cbuf  = (float*)(ws + C_OFF);
    unsigned int*   ctr   = (unsigned int*)(ws + CTR_OFF);

    build_wpack<<<768, 256, 0, stream>>>(Whh, Wih, wpack);
    init_misc<<<1024, 256, 0, stream>>>(bih, bhh, bias, (unsigned int*)(ws + H0_OFF), ctr);

    // persistent cooperative kernel; fall back to per-step launches if rejected
    const float* xa = x; const unsigned short* wa = wpack; const float* ba = bias;
    unsigned short* h0a = h0; unsigned short* h1a = h1; unsigned int* ca = ctr;
    void* args[] = { (void*)&xa, (void*)&wa, (void*)&ba, (void*)&h0a, (void*)&h1a, (void*)&ca };
    hipError_t e = hipLaunchCooperativeKernel((const void*)lstm_persist,
                                              dim3(256), dim3(512), args, 0, stream);
    if (e != hipSuccess) {
        for (int t = 0; t < T_; ++t) {
            const unsigned short* hin = (t & 1) ? h1 : h0;
            unsigned short*      hout = (t & 1) ? h0 : h1;
            lstm_step<<<dim3(4, 16), 256, 0, stream>>>(x, wpack, bias, hin, hout, cbuf, t);
        }
    }
    classify<<<1, 256, 0, stream>>>(h0, Wout, bout, out);
}

// Round 3
// 5699.155 us; speedup vs baseline: 2.1036x; 2.1036x over previous
//
#include <hip/hip_runtime.h>
#include <hip/hip_bf16.h>

#define B_  256
#define T_  1024
#define D_  256
#define H_  512
#define G_  2048   // 4*H
#define KT_ 768    // H + D

// ws layout (bytes)
#define WPACK_OFF 0                        // 2048*768*2 = 3145728
#define BIAS_OFF  3145728                  // 2048*4     = 8192
#define H0_OFF    (BIAS_OFF + 8192)        // 256*512*2  = 262144
#define H1_OFF    (H0_OFF + 262144)
#define C_OFF     (H1_OFF + 262144)        // 256*512*4  = 524288 (fallback path only)
#define FLAG_OFF  (C_OFF + 524288)         // 256 flags x 16 uints = 16384 bytes

typedef __attribute__((ext_vector_type(8))) short bf16x8;
typedef __attribute__((ext_vector_type(4))) float f32x4;

__device__ __forceinline__ unsigned short f2bf(float f) {
    unsigned int u = __float_as_uint(f);
    u = (u + 0x7fffu + ((u >> 16) & 1u)) >> 16;   // RNE
    return (unsigned short)u;
}
__device__ __forceinline__ float bf2f(unsigned short s) {
    return __uint_as_float(((unsigned int)s) << 16);
}
__device__ __forceinline__ float sigm(float v) { return 1.0f / (1.0f + __expf(-v)); }
__device__ __forceinline__ float tanh_(float v) { return 2.0f / (1.0f + __expf(-2.0f * v)) - 1.0f; }

// ---- prep: pack [W_hh | W_ih] rows into bf16 Wpack[2048][768] ----
__global__ __launch_bounds__(256) void build_wpack(const float* __restrict__ Whh,
                                                   const float* __restrict__ Wih,
                                                   unsigned short* __restrict__ wpack) {
    int idx = blockIdx.x * 256 + threadIdx.x;      // 0..196607, each = 8 elems
    int g = idx / 96, cc = idx % 96, k = cc * 8;
    const float* src = (k < H_) ? (Whh + (size_t)g * H_ + k)
                                : (Wih + (size_t)g * D_ + (k - H_));
    union { unsigned short us[8]; uint4 v; } u;
#pragma unroll
    for (int i = 0; i < 8; ++i) u.us[i] = f2bf(src[i]);
    *(uint4*)(wpack + (size_t)idx * 8) = u.v;
}

// ---- prep: zero h0/h1/c, build bias, zero flags ----
__global__ __launch_bounds__(256) void init_misc(const float* __restrict__ bih,
                                                 const float* __restrict__ bhh,
                                                 float* __restrict__ bias,
                                                 unsigned int* __restrict__ zreg,
                                                 unsigned int* __restrict__ flags) {
    int gid = blockIdx.x * 256 + threadIdx.x;      // grid 1024 -> 262144
    zreg[gid] = 0u;                                // h0+h1+c region (1 MB)
    if (gid < G_) bias[gid] = bih[gid] + bhh[gid];
    if (gid < 4096) flags[gid] = 0u;
}

// ============ persistent cooperative LSTM ============
// grid 256: rg = bid&7 (rowgroup, 32 batch rows), cg = bid>>3 (16 j-cols).
// 512 threads = 8 waves; wave w: np = w>>1 (gate), rt = w&1 (16-row tile).
// W fragments (24 x bf16x8 = 96 VGPR) live in registers for the whole T loop.
// c lives in 1 reg/thread. h exchange via agent-scope relaxed atomics
// (coherent, L1/L2-bypass); sync via per-block padded flags (no RMW).
__global__ __launch_bounds__(512, 2) void lstm_persist(
    const float* __restrict__ x,
    const unsigned short* __restrict__ wpack,
    const float* __restrict__ bias,
    unsigned short* __restrict__ h0,
    unsigned short* __restrict__ h1,
    unsigned int* __restrict__ flags)
{
    __shared__ __align__(16) unsigned char As[32 * 1536];   // [32 rows][768 k] bf16, XOR-swizzled
    __shared__ float Pc[4][32][18];                          // per-gate partial sums
    __shared__ unsigned short Hs[32][16];                    // new h tile (bf16)

    const int tid  = threadIdx.x;
    const int lane = tid & 63, w = tid >> 6;
    const int np = w >> 1, rt = w & 1;
    const int rg = blockIdx.x & 7, cg = blockIdx.x >> 3;     // rowgroup on one XCD (heuristic)
    const int r0 = rg * 32;

    // ---- load this wave's W fragments into registers (once) ----
    bf16x8 bfr[24];
    {
        const unsigned short* wrow = wpack + (size_t)(np * H_ + cg * 16 + (lane & 15)) * KT_
                                           + ((lane >> 4) * 8);
#pragma unroll
        for (int ks = 0; ks < 24; ++ks) bfr[ks] = *(const bf16x8*)(wrow + ks * 32);
    }

    // ---- per-thread epilogue constants ----
    const int erow = tid >> 4;        // 0..31
    const int ejj  = tid & 15;
    const float bI = bias[0 * H_ + cg * 16 + ejj];
    const float bF = bias[1 * H_ + cg * 16 + ejj];
    const float bG = bias[2 * H_ + cg * 16 + ejj];
    const float bO = bias[3 * H_ + cg * 16 + ejj];
    float c_reg = 0.f;

    const int arow = rt * 16 + (lane & 15);
    const int koff = (lane >> 4) * 16;     // byte offset within 64B k-step
    const int asw  = (arow & 7) << 4;

    // ---- x prefetch (normal cached loads) ----
    const int xrow = tid >> 4;             // 0..31
    const int xd0  = (tid & 15) * 16;      // float index within row
    const float* xbase = x + (size_t)(r0 + xrow) * T_ * D_ + xd0;
    float4 pa = *(const float4*)(xbase + 0);
    float4 pb = *(const float4*)(xbase + 4);
    float4 pc2 = *(const float4*)(xbase + 8);
    float4 pd = *(const float4*)(xbase + 12);

    unsigned int* myflag   = flags + (size_t)(rg * 32 + cg) * 16;
    unsigned int* pollflag = flags + (size_t)(rg * 32 + (lane & 31)) * 16;

    for (int t = 0; t < T_; ++t) {
        const unsigned short* hin = (t & 1) ? h1 : h0;
        unsigned short*      hout = (t & 1) ? h0 : h1;

        // 1: stage x(t) from prefetched regs -> As.x (k 512..767)
        {
            union { unsigned short us[8]; uint4 v; } u0, u1;
            u0.us[0] = f2bf(pa.x);  u0.us[1] = f2bf(pa.y);  u0.us[2] = f2bf(pa.z);  u0.us[3] = f2bf(pa.w);
            u0.us[4] = f2bf(pb.x);  u0.us[5] = f2bf(pb.y);  u0.us[6] = f2bf(pb.z);  u0.us[7] = f2bf(pb.w);
            u1.us[0] = f2bf(pc2.x); u1.us[1] = f2bf(pc2.y); u1.us[2] = f2bf(pc2.z); u1.us[3] = f2bf(pc2.w);
            u1.us[4] = f2bf(pd.x);  u1.us[5] = f2bf(pd.y);  u1.us[6] = f2bf(pd.z);  u1.us[7] = f2bf(pd.w);
            int kb = 1024 + xd0 * 2;
            int xsw = (xrow & 7) << 4;
            *(uint4*)(As + ((xrow * 1536 + kb) ^ xsw))      = u0.v;
            *(uint4*)(As + ((xrow * 1536 + kb + 16) ^ xsw)) = u1.v;
        }
        __syncthreads();

        // 3: x-part MFMAs (ks 16..23) -- no h dependency; hides barrier wait
        f32x4 acc0 = {0.f, 0.f, 0.f, 0.f}, acc1 = {0.f, 0.f, 0.f, 0.f};
#pragma unroll
        for (int ks = 16; ks < 24; ks += 2) {
            bf16x8 av0 = *(const bf16x8*)(As + ((arow * 1536 + ks * 64 + koff) ^ asw));
            bf16x8 av1 = *(const bf16x8*)(As + ((arow * 1536 + (ks + 1) * 64 + koff) ^ asw));
            acc0 = __builtin_amdgcn_mfma_f32_16x16x32_bf16(av0, bfr[ks], acc0, 0, 0, 0);
            acc1 = __builtin_amdgcn_mfma_f32_16x16x32_bf16(av1, bfr[ks + 1], acc1, 0, 0, 0);
        }

        // 4: wave 0 polls the 32 rowgroup flags (parallel lanes, no RMW)
        if (w == 0 && t > 0) {
            while (true) {
                unsigned int f = __hip_atomic_load(pollflag, __ATOMIC_RELAXED,
                                                   __HIP_MEMORY_SCOPE_AGENT);
                if (__all((int)(f >= (unsigned)t))) break;
                __builtin_amdgcn_s_sleep(1);
            }
        }
        __syncthreads();

        // 6: coherent-load h(t) -> As.h ; prefetch x(t+1) into regs
#pragma unroll
        for (int p = 0; p < 8; ++p) {
            int c = p * 512 + tid;            // 0..4095 chunks of 8B
            int row = c >> 7, off = c & 127;
            unsigned long long v = __hip_atomic_load(
                (const unsigned long long*)(hin + (size_t)(r0 + row) * H_) + off,
                __ATOMIC_RELAXED, __HIP_MEMORY_SCOPE_AGENT);
            *(unsigned long long*)(As + ((row * 1536 + off * 8) ^ ((row & 7) << 4))) = v;
        }
        if (t + 1 < T_) {
            const float* sp = xbase + (size_t)(t + 1) * D_;
            pa = *(const float4*)(sp + 0);
            pb = *(const float4*)(sp + 4);
            pc2 = *(const float4*)(sp + 8);
            pd = *(const float4*)(sp + 12);
        }
        __syncthreads();

        // 8: h-part MFMAs (ks 0..15)
#pragma unroll
        for (int ks = 0; ks < 16; ks += 2) {
            bf16x8 av0 = *(const bf16x8*)(As + ((arow * 1536 + ks * 64 + koff) ^ asw));
            bf16x8 av1 = *(const bf16x8*)(As + ((arow * 1536 + (ks + 1) * 64 + koff) ^ asw));
            acc0 = __builtin_amdgcn_mfma_f32_16x16x32_bf16(av0, bfr[ks], acc0, 0, 0, 0);
            acc1 = __builtin_amdgcn_mfma_f32_16x16x32_bf16(av1, bfr[ks + 1], acc1, 0, 0, 0);
        }
        // dump partials (C layout: col=lane&15, row=(lane>>4)*4+reg)
#pragma unroll
        for (int reg = 0; reg < 4; ++reg) {
            int crow = rt * 16 + ((lane >> 4) * 4) + reg;
            Pc[np][crow][lane & 15] = acc0[reg] + acc1[reg];
        }
        __syncthreads();

        // 10: cell update; thread owns (erow, ejj); c stays in register
        {
            float gi = Pc[0][erow][ejj] + bI;
            float gf = Pc[1][erow][ejj] + bF;
            float gg = Pc[2][erow][ejj] + bG;
            float go = Pc[3][erow][ejj] + bO;
            float I = sigm(gi), F = sigm(gf), Gv = tanh_(gg), O = sigm(go);
            c_reg = F * c_reg + I * Gv;
            Hs[erow][ejj] = f2bf(O * tanh_(c_reg));
        }
        __syncthreads();

        // 12: coherent-store h(t+1) tile (1KB, 8B chunks)
        if (tid < 128) {
            int row = tid >> 2, part = tid & 3;
            unsigned long long v = *(const unsigned long long*)(&Hs[row][part * 4]);
            __hip_atomic_store(
                (unsigned long long*)(hout + (size_t)(r0 + row) * H_ + cg * 16 + part * 4),
                v, __ATOMIC_RELAXED, __HIP_MEMORY_SCOPE_AGENT);
        }
        __syncthreads();   // drains stores (vmcnt 0) before flag

        // 14: publish step completion (own flag only; no contention)
        if (tid == 0)
            __hip_atomic_store(myflag, (unsigned)(t + 1), __ATOMIC_RELEASE,
                               __HIP_MEMORY_SCOPE_AGENT);
    }
}

// ============ fallback per-step kernel (round-1, known passing) ============
__global__ __launch_bounds__(256) void lstm_step(const float* __restrict__ x,
                                                 const unsigned short* __restrict__ wpack,
                                                 const float* __restrict__ bias,
                                                 const unsigned short* __restrict__ hin,
                                                 unsigned short* __restrict__ hout,
                                                 float* __restrict__ cbuf,
                                                 int t) {
    __shared__ __align__(16) unsigned char As[64 * 1536];
    __shared__ __align__(16) unsigned char Ws[128 * 256];

    const int tid = threadIdx.x;
    const int w = tid >> 6, lane = tid & 63;
    const int r0 = blockIdx.x * 64;
    const int j0 = blockIdx.y * 32;

#pragma unroll
    for (int p = 0; p < 16; ++p) {
        int idx = p * 256 + tid;
        int row = idx >> 6, seg = idx & 63;
        uint4 v = *(const uint4*)(hin + (size_t)(r0 + row) * H_ + seg * 8);
        *(uint4*)(As + (((row * 1536) + seg * 16) ^ ((row & 7) << 4))) = v;
    }
#pragma unroll
    for (int p = 0; p < 8; ++p) {
        int idx = p * 256 + tid;
        int row = idx >> 5, seg = idx & 31;
        const float* sp = x + ((size_t)(r0 + row) * T_ + t) * D_ + seg * 8;
        float4 a = *(const float4*)sp;
        float4 b = *(const float4*)(sp + 4);
        union { unsigned short us[8]; uint4 v; } u;
        u.us[0] = f2bf(a.x); u.us[1] = f2bf(a.y); u.us[2] = f2bf(a.z); u.us[3] = f2bf(a.w);
        u.us[4] = f2bf(b.x); u.us[5] = f2bf(b.y); u.us[6] = f2bf(b.z); u.us[7] = f2bf(b.w);
        *(uint4*)(As + (((row * 1536) + 1024 + seg * 16) ^ ((row & 7) << 4))) = u.v;
    }
    __syncthreads();

    f32x4 acc[8];
#pragma unroll
    for (int i = 0; i < 8; ++i) acc[i] = (f32x4){0.f, 0.f, 0.f, 0.f};

    for (int kc = 0; kc < 6; ++kc) {
#pragma unroll
        for (int p = 0; p < 8; ++p) {
            int idx = p * 256 + tid;
            int n = idx >> 4, seg = idx & 15;
            int g = n >> 5, jj = n & 31;
            uint4 v = *(const uint4*)(wpack + (size_t)(g * H_ + j0 + jj) * KT_ + kc * 128 + seg * 8);
            *(uint4*)(Ws + (((n * 256) + seg * 16) ^ ((n & 7) << 4))) = v;
        }
        __syncthreads();
#pragma unroll
        for (int ks = 0; ks < 4; ++ks) {
            int row = w * 16 + (lane & 15);
            int kb = (kc * 128 + ks * 32 + ((lane >> 4) * 8)) * 2;
            bf16x8 av = *(const bf16x8*)(As + ((row * 1536 + kb) ^ ((row & 7) << 4)));
            int kwb = (ks * 32 + ((lane >> 4) * 8)) * 2;
#pragma unroll
            for (int nt = 0; nt < 8; ++nt) {
                int n = (nt >> 1) * 32 + (nt & 1) * 16 + (lane & 15);
                bf16x8 bv = *(const bf16x8*)(Ws + ((n * 256 + kwb) ^ ((n & 7) << 4)));
                acc[nt] = __builtin_amdgcn_mfma_f32_16x16x32_bf16(av, bv, acc[nt], 0, 0, 0);
            }
        }
        __syncthreads();
    }

#pragma unroll
    for (int jt = 0; jt < 2; ++jt) {
        int jc = j0 + jt * 16 + (lane & 15);
        float bi = bias[jc], bf = bias[H_ + jc], bg = bias[2 * H_ + jc], bo = bias[3 * H_ + jc];
        f32x4 ai = acc[0 * 2 + jt];
        f32x4 af = acc[1 * 2 + jt];
        f32x4 ag = acc[2 * 2 + jt];
        f32x4 ao = acc[3 * 2 + jt];
#pragma unroll
        for (int reg = 0; reg < 4; ++reg) {
            int rb = r0 + w * 16 + ((lane >> 4) * 4) + reg;
            float I = sigm(ai[reg] + bi);
            float F = sigm(af[reg] + bf);
            float Gv = tanh_(ag[reg] + bg);
            float O = sigm(ao[reg] + bo);
            size_t ci = (size_t)rb * H_ + jc;
            float cn = F * cbuf[ci] + I * Gv;
            cbuf[ci] = cn;
            hout[ci] = f2bf(O * tanh_(cn));
        }
    }
}

// ---- final: out = sigmoid(h @ W_out^T + b_out), [256,2] ----
__global__ __launch_bounds__(256) void classify(const unsigned short* __restrict__ hbuf,
                                                const float* __restrict__ Wout,
                                                const float* __restrict__ bout,
                                                float* __restrict__ out) {
    int r = threadIdx.x;
    float a0 = 0.f, a1 = 0.f;
    for (int kk = 0; kk < H_ / 8; ++kk) {
        union { unsigned short us[8]; uint4 v; } u;
        u.v = *(const uint4*)(hbuf + (size_t)r * H_ + kk * 8);
#pragma unroll
        for (int i = 0; i < 8; ++i) {
            float hf = bf2f(u.us[i]);
            int k = kk * 8 + i;
            a0 += hf * Wout[k];
            a1 += hf * Wout[H_ + k];
        }
    }
    out[r * 2 + 0] = sigm(a0 + bout[0]);
    out[r * 2 + 1] = sigm(a1 + bout[1]);
}

extern "C" void kernel_launch(void* const* d_in, const int* in_sizes, int n_in,
                              void* d_out, int out_size, void* d_ws, size_t ws_size,
                              hipStream_t stream) {
    const float* x    = (const float*)d_in[0];
    const float* Wih  = (const float*)d_in[1];
    const float* Whh  = (const float*)d_in[2];
    const float* bih  = (const float*)d_in[3];
    const float* bhh  = (const float*)d_in[4];
    const float* Wout = (const float*)d_in[5];
    const float* bout = (const float*)d_in[6];
    float* out = (float*)d_out;
    char* ws = (char*)d_ws;

    unsigned short* wpack = (unsigned short*)(ws + WPACK_OFF);
    float*          bias  = (float*)(ws + BIAS_OFF);
    unsigned short* h0    = (unsigned short*)(ws + H0_OFF);
    unsigned short* h1    = (unsigned short*)(ws + H1_OFF);
    float*          cbuf  = (float*)(ws + C_OFF);
    unsigned int*   flags = (unsigned int*)(ws + FLAG_OFF);

    build_wpack<<<768, 256, 0, stream>>>(Whh, Wih, wpack);
    init_misc<<<1024, 256, 0, stream>>>(bih, bhh, bias, (unsigned int*)(ws + H0_OFF), flags);

    // persistent cooperative kernel; fall back to per-step launches if rejected
    const float* xa = x; const unsigned short* wa = wpack; const float* ba = bias;
    unsigned short* h0a = h0; unsigned short* h1a = h1; unsigned int* fa = flags;
    void* args[] = { (void*)&xa, (void*)&wa, (void*)&ba, (void*)&h0a, (void*)&h1a, (void*)&fa };
    hipError_t e = hipLaunchCooperativeKernel((const void*)lstm_persist,
                                              dim3(256), dim3(512), args, 0, stream);
    if (e != hipSuccess) {
        for (int t = 0; t < T_; ++t) {
            const unsigned short* hin = (t & 1) ? h1 : h0;
            unsigned short*      hout = (t & 1) ? h0 : h1;
            lstm_step<<<dim3(4, 16), 256, 0, stream>>>(x, wpack, bias, hin, hout, cbuf, t);
        }
    }
    classify<<<1, 256, 0, stream>>>(h0, Wout, bout, out);
}